// Round 7
// baseline (429.280 us; speedup 1.0000x reference)
//
#include <hip/hip_runtime.h>
#include <math.h>

#define NB 2
#define NL 1024
#define ND 768
#define NH 12
#define DH 64

typedef _Float16 f16;
typedef _Float16 f16x4 __attribute__((ext_vector_type(4)));
typedef _Float16 f16x8 __attribute__((ext_vector_type(8)));
typedef float f32x4 __attribute__((ext_vector_type(4)));

#define MFMA16(a, b, c) __builtin_amdgcn_mfma_f32_16x16x32_f16((a), (b), (c), 0, 0, 0)

// LDS-only barrier (does not force vmcnt drain).
__device__ __forceinline__ void soft_barrier() {
    asm volatile("s_waitcnt lgkmcnt(0)\n\ts_barrier" ::: "memory");
}

// ---------------------------------------------------------------------------
// Kernel 0: prep.
//   tiles 0..767    : hs fp32 -> hsf f16
//   tiles 768..1199 : W{q,k,v} -> wt f16 [(mat*12+h)*64+n][k]   (transposed)
//   tiles 1200..1263: dist_emb fp32 -> de16 f16
// ---------------------------------------------------------------------------
__global__ __launch_bounds__(256) void prep_kernel(
    const float* __restrict__ hs,
    const float* __restrict__ Wq, const float* __restrict__ Wk,
    const float* __restrict__ Wv, const float* __restrict__ de,
    f16* __restrict__ hsf, f16* __restrict__ wt, f16* __restrict__ de16)
{
    __shared__ float sT[64 * 66];
    const int t = threadIdx.x;
    const int tile = blockIdx.x;

    if (tile < 768) {
        const int base = tile * 2048 + t * 8;
        float4 a = *(const float4*)&hs[base];
        float4 b = *(const float4*)&hs[base + 4];
        f16x8 hv;
        hv[0] = (f16)a.x; hv[1] = (f16)a.y; hv[2] = (f16)a.z; hv[3] = (f16)a.w;
        hv[4] = (f16)b.x; hv[5] = (f16)b.y; hv[6] = (f16)b.z; hv[7] = (f16)b.w;
        *(f16x8*)&hsf[base] = hv;
        return;
    }
    if (tile >= 1200) {
        const int base = (tile - 1200) * 2048 + t * 8;
        if (base < 2047 * 64) {
            float4 a = *(const float4*)&de[base];
            float4 b = *(const float4*)&de[base + 4];
            f16x8 hv;
            hv[0] = (f16)a.x; hv[1] = (f16)a.y; hv[2] = (f16)a.z; hv[3] = (f16)a.w;
            hv[4] = (f16)b.x; hv[5] = (f16)b.y; hv[6] = (f16)b.z; hv[7] = (f16)b.w;
            *(f16x8*)&de16[base] = hv;
        }
        return;
    }

    // W transpose: ti in 0..431
    const int ti = tile - 768;
    const int mat = ti / 144, r2 = ti % 144, ht = r2 / 12, kt = r2 % 12;
    const float* W = (mat == 0) ? Wq : (mat == 1) ? Wk : Wv;
    const float* S = W + (size_t)(kt * 64) * ND + ht * 64;
    f16* D = wt + (size_t)((mat * NH + ht) * 64) * ND + kt * 64;

    {
        const int kk = t >> 2, nb = (t & 3) * 16;
        float v[16];
        #pragma unroll
        for (int j = 0; j < 4; ++j)
            *(float4*)&v[4 * j] = *(const float4*)&S[(size_t)kk * ND + nb + 4 * j];
        #pragma unroll
        for (int jj = 0; jj < 16; ++jj)
            sT[(nb + jj) * 66 + kk] = v[jj];
    }
    soft_barrier();
    {
        const int n = t >> 2, kb = (t & 3) * 16;
        f16 tmp[16];
        #pragma unroll
        for (int j = 0; j < 8; ++j) {
            float2 x = *(float2*)&sT[n * 66 + kb + 2 * j];
            tmp[2 * j]     = (f16)x.x;
            tmp[2 * j + 1] = (f16)x.y;
        }
        *(f16x8*)&D[(size_t)n * ND + kb]     = *(f16x8*)&tmp[0];
        *(f16x8*)&D[(size_t)n * ND + kb + 8] = *(f16x8*)&tmp[8];
    }
}

// ---------------------------------------------------------------------------
// Kernel W5: W'[p,h] = Wq[:, h-block] @ sw[p,h]  (768x64x64 fp32),
// written transposed as wq5t[(p*12+h)][e][k] f16; bq5[p,h,e] = bq_h . sw[p,h].
// Grid (12 row-tiles, 60 (p,h)).
// ---------------------------------------------------------------------------
__global__ __launch_bounds__(256, 2) void wq5_kernel(
    const float* __restrict__ Wq, const float* __restrict__ bq,
    const float* __restrict__ sw,
    f16* __restrict__ wq5t, float* __restrict__ bq5)
{
    __shared__ float sAT[64 * 69];   // [d][kk]
    __shared__ float sB[64 * 64];    // [d][e]
    __shared__ float sT[64 * 66];    // bounce [e][kk]

    const int ktile = blockIdx.x;    // 0..11
    const int z  = blockIdx.y;       // 0..59 = p*12+h
    const int h  = z % NH;
    const int k0 = ktile * 64;
    const int t  = threadIdx.x;

    {
        const int kk = t >> 2, db = (t & 3) * 16;
        float v[16];
        #pragma unroll
        for (int j = 0; j < 4; ++j)
            *(float4*)&v[4 * j] = *(const float4*)&Wq[(size_t)(k0 + kk) * ND + h * 64 + db + 4 * j];
        #pragma unroll
        for (int jj = 0; jj < 16; ++jj)
            sAT[(db + jj) * 69 + kk] = v[jj];
        #pragma unroll
        for (int j = 0; j < 4; ++j)
            *(float4*)&sB[16 * t + 4 * j] = *(const float4*)&sw[(size_t)z * 4096 + 16 * t + 4 * j];
    }
    soft_barrier();

    const int tr = t >> 4, tc = t & 15;
    float acc[4][4];
    #pragma unroll
    for (int r = 0; r < 4; ++r)
        #pragma unroll
        for (int c = 0; c < 4; ++c) acc[r][c] = 0.f;

    #pragma unroll 8
    for (int d = 0; d < 64; ++d) {
        float a[4], b[4];
        *(float4*)a = *(const float4*)&sAT[d * 69 + tr * 4];
        *(float4*)b = *(const float4*)&sB[d * 64 + tc * 4];
        #pragma unroll
        for (int r = 0; r < 4; ++r)
            #pragma unroll
            for (int c = 0; c < 4; ++c)
                acc[r][c] += a[r] * b[c];
    }

    if (ktile == 0 && t < 64) {
        float s = 0.f;
        for (int d = 0; d < 64; ++d) s += bq[h * 64 + d] * sB[d * 64 + t];
        bq5[z * 64 + t] = s;
    }

    // transpose bounce: sT[e][kk]
    #pragma unroll
    for (int r = 0; r < 4; ++r)
        #pragma unroll
        for (int c = 0; c < 4; ++c)
            sT[(tc * 4 + c) * 66 + tr * 4 + r] = acc[r][c];
    soft_barrier();

    const int e = t >> 2, kb = (t & 3) * 16;
    f16 tmp[16];
    #pragma unroll
    for (int j = 0; j < 8; ++j) {
        float2 x = *(float2*)&sT[e * 66 + kb + 2 * j];
        tmp[2 * j] = (f16)x.x; tmp[2 * j + 1] = (f16)x.y;
    }
    f16* dst = wq5t + ((size_t)z * 64 + e) * ND + k0 + kb;
    *(f16x8*)dst       = *(f16x8*)&tmp[0];
    *(f16x8*)(dst + 8) = *(f16x8*)&tmp[8];
}

// ---------------------------------------------------------------------------
// Kernel A: unified projection, f16 MFMA.  Grid (32, 96):
//   y<36 : q/k/v  (B = wt[y]);  y>=36: qw[p,h] (B = wq5t[y-36], bias bq5).
// 64x64 tile, 4 waves, 2x2 subtiles/wave, 12 K-steps of 64.
// ---------------------------------------------------------------------------
__global__ __launch_bounds__(256, 4) void proj_kernel(
    const f16* __restrict__ hsf, const f16* __restrict__ wt,
    const f16* __restrict__ wq5t, const float* __restrict__ bq5,
    const float* __restrict__ bq, const float* __restrict__ bk,
    const float* __restrict__ bv,
    f16* __restrict__ qf, f16* __restrict__ kf, f16* __restrict__ vt,
    f16* __restrict__ qwf)
{
    __shared__ f16 sA[64 * 72], sB[64 * 72];
    __shared__ float sT[64 * 66];

    const int m0  = blockIdx.x * 64;
    const int y   = blockIdx.y;          // 0..95
    const bool isqw = (y >= 36);
    const int mat = isqw ? 3 : y / NH;
    const int z2  = isqw ? (y - 36) : 0; // p*12+h
    const int h   = isqw ? (z2 % NH) : (y % NH);
    const int t = threadIdx.x, lane = t & 63, w = t >> 6;
    const int quad = lane >> 4, l15 = lane & 15;
    const int wm = w >> 1, wn = w & 1;

    const float* bias = (mat == 0) ? bq : (mat == 1) ? bk : bv;

    f32x4 acc[2][2];
    #pragma unroll
    for (int r = 0; r < 2; ++r)
        #pragma unroll
        for (int c = 0; c < 2; ++c) acc[r][c] = (f32x4){0.f, 0.f, 0.f, 0.f};

    const int srow = t >> 2, scol = (t & 3) * 16;
    const f16* Ag = hsf + (size_t)(m0 + srow) * ND + scol;
    const f16* Bg = (isqw ? wq5t + (size_t)z2 * 64 * ND : wt + (size_t)y * 64 * ND)
                    + (size_t)srow * ND + scol;

    for (int k0 = 0; k0 < ND; k0 += 64) {
        soft_barrier();
        *(f16x8*)&sA[srow * 72 + scol]     = *(const f16x8*)&Ag[k0];
        *(f16x8*)&sA[srow * 72 + scol + 8] = *(const f16x8*)&Ag[k0 + 8];
        *(f16x8*)&sB[srow * 72 + scol]     = *(const f16x8*)&Bg[k0];
        *(f16x8*)&sB[srow * 72 + scol + 8] = *(const f16x8*)&Bg[k0 + 8];
        soft_barrier();
        #pragma unroll
        for (int kk = 0; kk < 64; kk += 32) {
            const int ko = kk + quad * 8;
            f16x8 a0 = *(f16x8*)&sA[(32 * wm + l15) * 72 + ko];
            f16x8 a1 = *(f16x8*)&sA[(32 * wm + 16 + l15) * 72 + ko];
            f16x8 b0 = *(f16x8*)&sB[(32 * wn + l15) * 72 + ko];
            f16x8 b1 = *(f16x8*)&sB[(32 * wn + 16 + l15) * 72 + ko];
            acc[0][0] = MFMA16(a0, b0, acc[0][0]);
            acc[0][1] = MFMA16(a0, b1, acc[0][1]);
            acc[1][0] = MFMA16(a1, b0, acc[1][0]);
            acc[1][1] = MFMA16(a1, b1, acc[1][1]);
        }
    }
    soft_barrier();

    const int bb = m0 >> 10;
    const int lbase = m0 & 1023;
    const int bh = bb * NH + h;

    if (mat == 2) {
        // v: transpose to [bh][d][l]
        #pragma unroll
        for (int r = 0; r < 2; ++r)
            #pragma unroll
            for (int c = 0; c < 2; ++c) {
                const int col = 32 * wn + 16 * c + l15;
                const float bz = bias[h * 64 + col];
                #pragma unroll
                for (int rr = 0; rr < 4; ++rr)
                    sT[col * 66 + 32 * wm + 16 * r + 4 * quad + rr] = acc[r][c][rr] + bz;
            }
        soft_barrier();
        const int d = t >> 2, lcb = (t & 3) * 16;
        f16 tmp[16];
        #pragma unroll
        for (int j = 0; j < 8; ++j) {
            float2 x = *(float2*)&sT[d * 66 + lcb + 2 * j];
            tmp[2 * j] = (f16)x.x; tmp[2 * j + 1] = (f16)x.y;
        }
        f16* dst = vt + ((size_t)bh * DH + d) * NL + lbase + lcb;
        *(f16x8*)dst       = *(f16x8*)&tmp[0];
        *(f16x8*)(dst + 8) = *(f16x8*)&tmp[8];
    } else {
        #pragma unroll
        for (int r = 0; r < 2; ++r)
            #pragma unroll
            for (int c = 0; c < 2; ++c) {
                const int col = 32 * wn + 16 * c + l15;
                const float bz = isqw ? bq5[z2 * 64 + col] : bias[h * 64 + col];
                #pragma unroll
                for (int rr = 0; rr < 4; ++rr)
                    sT[(32 * wm + 16 * r + 4 * quad + rr) * 66 + col] = acc[r][c][rr] + bz;
            }
        soft_barrier();
        const int orow = t >> 2, ocb = (t & 3) * 16;
        f16 tmp[16];
        #pragma unroll
        for (int j = 0; j < 8; ++j) {
            float2 x = *(float2*)&sT[orow * 66 + ocb + 2 * j];
            tmp[2 * j] = (f16)x.x; tmp[2 * j + 1] = (f16)x.y;
        }
        f16* dst;
        if (isqw) {
            const int p = z2 / NH;
            dst = qwf + ((size_t)(p * 24 + bh) * NL + lbase + orow) * DH + ocb;
        } else {
            dst = ((mat == 0) ? qf : kf) + ((size_t)bh * NL + lbase + orow) * DH + ocb;
        }
        *(f16x8*)dst       = *(f16x8*)&tmp[0];
        *(f16x8*)(dst + 8) = *(f16x8*)&tmp[8];
    }
}

// ---------------------------------------------------------------------------
// Kernel C: f16-MFMA flash attention, 512 threads (8 waves), q-tile 32,
// k-tile 64.  Wave w: msub = w>>2 (i-block), ncol = w&3 (j-block 16).
// Fused pos band-GEMMs distributed flat over waves; QE/KE scratch stored
// row-major [i][tp] pitch 100 (<=2-way banks both store and gather).
// ---------------------------------------------------------------------------
__global__ __launch_bounds__(512, 4) void attn_kernel(
    const f16* __restrict__ qf, const f16* __restrict__ kf,
    const f16* __restrict__ vt, const f16* __restrict__ qwf,
    const float* __restrict__ mask, const float* __restrict__ struct_m,
    const f16* __restrict__ de16, const float* __restrict__ abs_bias,
    float* __restrict__ out)
{
    __shared__ f16 sQ[32 * 72];
    __shared__ f16 sK[64 * 72];
    __shared__ f16 sVt[2][64 * 72];
    __shared__ f16 sE[96 * 72];      // E band rows 0..94 (t' = i-j+63)
    __shared__ f16 sQEl[32 * 100];   // [i][tp]
    __shared__ f16 sKEl[64 * 100];   // [j][tp]
    __shared__ float sS[32 * 68];
    __shared__ f16 sP[32 * 72];
    __shared__ float sAlpha[32], sL[32];

    const int l0 = blockIdx.x * 32;
    const int bh = blockIdx.y;
    const int bb = bh / NH, h = bh % NH;
    const int t  = threadIdx.x;
    const int lane = t & 63;
    const int w    = t >> 6;        // 0..7
    const int quad = lane >> 4;
    const int l15  = lane & 15;
    const int msub = w >> 2;        // 0..1
    const int ncol = w & 3;         // 0..3

    const size_t NQKV = (size_t)NB * NH * NL * DH;

    // resident A-fragments for this wave's i-block
    f16x8 aQ[2], aW[5][2];
    {
        const size_t qrow = ((size_t)bh * NL + l0 + 16 * msub + l15) * DH;
        #pragma unroll
        for (int K = 0; K < 2; ++K) {
            aQ[K] = *(const f16x8*)&qf[qrow + 32 * K + 8 * quad];
            #pragma unroll
            for (int p = 0; p < 5; ++p)
                aW[p][K] = *(const f16x8*)&qwf[p * NQKV + qrow + 32 * K + 8 * quad];
        }
    }
    // sQ stage (once)
    if (t < 256) {
        const int row = t >> 3, col = (t & 7) * 8;
        *(f16x8*)&sQ[row * 72 + col] =
            *(const f16x8*)&qf[((size_t)bh * NL + l0 + row) * DH + col];
    }

    float ab[5];
    #pragma unroll
    for (int p = 0; p < 5; ++p) ab[p] = abs_bias[p * NH + h];

    float pf_st[5][4], pf_mask;

    auto stage_kv = [&](int r0s, int buf) {
        const int row = t >> 3, col = (t & 7) * 8;
        *(f16x8*)&sK[row * 72 + col] =
            *(const f16x8*)&kf[((size_t)bh * NL + r0s + row) * DH + col];
        *(f16x8*)&sVt[buf][row * 72 + col] =
            *(const f16x8*)&vt[((size_t)bh * DH + row) * NL + r0s + col];
    };
    auto stage_E = [&](int r0s) {
        const int ebase = l0 - r0s + 960;
        #pragma unroll
        for (int p2 = 0; p2 < 2; ++p2) {
            const int idx = t + 512 * p2;
            const int er = idx >> 3, col = (idx & 7) * 8;
            if (er < 95)
                *(f16x8*)&sE[er * 72 + col] =
                    *(const f16x8*)&de16[(size_t)(ebase + er) * DH + col];
        }
    };
    auto prefetch = [&](int r0s) {
        const int j = 16 * ncol + l15;
        pf_mask = mask[bb * NL + r0s + j];
        #pragma unroll
        for (int r = 0; r < 4; ++r) {
            const int i = 16 * msub + 4 * quad + r;
            #pragma unroll
            for (int p = 0; p < 5; ++p)
                pf_st[p][r] =
                    struct_m[((size_t)(p * NB + bb) * NL + l0 + i) * NL + r0s + j];
        }
    };

    stage_kv(0, 0);
    stage_E(0);
    prefetch(0);

    const int sm_i = t >> 4;    // 0..31
    const int sm_c = t & 15;    // 0..15
    float m_cur = -INFINITY, l_cur = 0.f;
    f32x4 O = (f32x4){0.f, 0.f, 0.f, 0.f};

    for (int kt = 0; kt < 16; ++kt) {
        const int cur = kt & 1;
        soft_barrier();                    // staging of this kt visible

        // ---- Phase B: pos band GEMM tiles, flat over waves ----
        #pragma unroll
        for (int c = 0; c < 5; ++c) {
            const int tid = c * 8 + w;     // 0..39, valid < 36
            if (tid < 36) {
                const bool isq = (tid < 12);
                const int u  = isq ? tid : tid - 12;
                const int rt = u / 6;      // mi (0..1) or jt (0..3)
                const int nt = u % 6;
                const f16* abase = isq ? &sQ[(16 * rt + l15) * 72]
                                       : &sK[(16 * rt + l15) * 72];
                f16x8 a0 = *(f16x8*)&abase[quad * 8];
                f16x8 a1 = *(f16x8*)&abase[32 + quad * 8];
                f16x8 e0 = *(f16x8*)&sE[(16 * nt + l15) * 72 + quad * 8];
                f16x8 e1 = *(f16x8*)&sE[(16 * nt + l15) * 72 + 32 + quad * 8];
                f32x4 cq = (f32x4){0.f, 0.f, 0.f, 0.f};
                cq = MFMA16(a0, e0, cq);
                cq = MFMA16(a1, e1, cq);
                f16* dstp = isq ? sQEl : sKEl;
                const int row0 = 16 * rt + 4 * quad;
                #pragma unroll
                for (int r = 0; r < 4; ++r)
                    dstp[(row0 + r) * 100 + 16 * nt + l15] = (f16)cq[r];
            }
        }
        soft_barrier();                    // sQEl/sKEl published

        // ---- Phase C: score MFMAs + epilogue ----
        {
            f32x4 acc[6];
            #pragma unroll
            for (int p = 0; p < 6; ++p) acc[p] = (f32x4){0.f, 0.f, 0.f, 0.f};
            #pragma unroll
            for (int K = 0; K < 2; ++K) {
                const int koff = K * 32 + quad * 8;
                f16x8 bk2 = *(f16x8*)&sK[(16 * ncol + l15) * 72 + koff];
                acc[0] = MFMA16(aQ[K], bk2, acc[0]);
                #pragma unroll
                for (int p = 0; p < 5; ++p)
                    acc[1 + p] = MFMA16(aW[p][K], bk2, acc[1 + p]);
            }
            const int j = 16 * ncol + l15;
            #pragma unroll
            for (int r = 0; r < 4; ++r) {
                const int i = 16 * msub + 4 * quad + r;
                const int tp = i - j + 63;
                float posv = (float)sQEl[i * 100 + tp] + (float)sKEl[j * 100 + tp];
                float s = (acc[0][r] + posv) * 0.125f + pf_mask;
                #pragma unroll
                for (int p = 0; p < 5; ++p)
                    s += (acc[1 + p][r] + ab[p]) * pf_st[p][r];
                sS[i * 68 + j] = s;
            }
        }
        soft_barrier();                    // sS published

        // ---- Phase D: online softmax (32 rows x 16 threads) ----
        {
            float sv[4];
            float smax = -INFINITY;
            #pragma unroll
            for (int k = 0; k < 4; ++k) {
                sv[k] = sS[sm_i * 68 + sm_c + 16 * k];
                smax = fmaxf(smax, sv[k]);
            }
            #pragma unroll
            for (int off = 8; off > 0; off >>= 1)
                smax = fmaxf(smax, __shfl_xor(smax, off, 16));
            const float m_new = fmaxf(m_cur, smax);
            const float alpha = __expf(m_cur - m_new);
            float rsum = 0.f;
            #pragma unroll
            for (int k = 0; k < 4; ++k) {
                float p = __expf(sv[k] - m_new);
                sP[sm_i * 72 + sm_c + 16 * k] = (f16)p;
                rsum += p;
            }
            #pragma unroll
            for (int off = 8; off > 0; off >>= 1)
                rsum += __shfl_xor(rsum, off, 16);
            l_cur = l_cur * alpha + rsum;
            m_cur = m_new;
            if (sm_c == 0) { sAlpha[sm_i] = alpha; sL[sm_i] = l_cur; }
        }
        soft_barrier();                    // sP/alpha published

        // ---- Phase E: issue next-kt VMEM, then PV MFMA ----
        {
            if (kt < 15) {
                stage_kv((kt + 1) * 64, cur ^ 1);
                stage_E((kt + 1) * 64);
                prefetch((kt + 1) * 64);
            }
            float a4[4];
            #pragma unroll
            for (int r = 0; r < 4; ++r) a4[r] = sAlpha[16 * msub + 4 * quad + r];
            #pragma unroll
            for (int r = 0; r < 4; ++r) O[r] *= a4[r];

            #pragma unroll
            for (int K = 0; K < 2; ++K) {
                const int koff = K * 32 + quad * 8;
                f16x8 pfr = *(f16x8*)&sP[(16 * msub + l15) * 72 + koff];
                f16x8 vfr = *(f16x8*)&sVt[cur][(16 * ncol + l15) * 72 + koff];
                O = MFMA16(pfr, vfr, O);
            }
        }
    }

    float linv[4];
    #pragma unroll
    for (int r = 0; r < 4; ++r) linv[r] = 1.0f / sL[16 * msub + 4 * quad + r];
    const int dh = 16 * ncol + l15;
    #pragma unroll
    for (int r = 0; r < 4; ++r) {
        const int i = 16 * msub + 4 * quad + r;
        out[((size_t)bb * NL + l0 + i) * ND + h * DH + dh] = O[r] * linv[r];
    }
}

// ---------------------------------------------------------------------------
extern "C" void kernel_launch(void* const* d_in, const int* in_sizes, int n_in,
                              void* d_out, int out_size, void* d_ws, size_t ws_size,
                              hipStream_t stream) {
    const float* hs   = (const float*)d_in[0];
    const float* mask = (const float*)d_in[1];
    const float* stm  = (const float*)d_in[2];
    const float* Wq   = (const float*)d_in[3];
    const float* bq   = (const float*)d_in[4];
    const float* Wk   = (const float*)d_in[5];
    const float* bk   = (const float*)d_in[6];
    const float* Wv   = (const float*)d_in[7];
    const float* bv   = (const float*)d_in[8];
    const float* de   = (const float*)d_in[9];
    const float* sw   = (const float*)d_in[10];
    const float* abb  = (const float*)d_in[11];
    float* outp = (float*)d_out;

    const size_t NQKV = (size_t)NB * NH * NL * DH;       // 1,572,864
    char* ws = (char*)d_ws;
    f16*   qf   = (f16*)ws;               ws += NQKV * 2;
    f16*   kf   = (f16*)ws;               ws += NQKV * 2;
    f16*   vtb  = (f16*)ws;               ws += NQKV * 2;
    f16*   qwf  = (f16*)ws;               ws += 5 * NQKV * 2;
    f16*   hsf  = (f16*)ws;               ws += NQKV * 2;
    f16*   wt   = (f16*)ws;               ws += (size_t)2304 * 768 * 2;
    f16*   wq5t = (f16*)ws;               ws += (size_t)60 * 64 * 768 * 2;
    float* bq5  = (float*)ws;             ws += 3840 * 4;
    f16*   de16 = (f16*)ws;               // 2047*64 f16 = 262 KB

    prep_kernel<<<1264, 256, 0, stream>>>(hs, Wq, Wk, Wv, de, hsf, wt, de16);
    wq5_kernel<<<dim3(12, 60), 256, 0, stream>>>(Wq, bq, sw, wq5t, bq5);
    proj_kernel<<<dim3(32, 96), 256, 0, stream>>>(hsf, wt, wq5t, bq5,
                                                  bq, bk, bv, qf, kf, vtb, qwf);
    attn_kernel<<<dim3(32, 24), 512, 0, stream>>>(qf, kf, vtb, qwf,
                                                  mask, stm, de16, abb, outp);
}

// Round 8
// 237.681 us; speedup vs baseline: 1.8061x; 1.8061x over previous
//
#include <hip/hip_runtime.h>
#include <math.h>

#define NB 2
#define NL 1024
#define ND 768
#define NH 12
#define DH 64

typedef _Float16 f16;
typedef _Float16 f16x2 __attribute__((ext_vector_type(2)));
typedef _Float16 f16x4 __attribute__((ext_vector_type(4)));
typedef _Float16 f16x8 __attribute__((ext_vector_type(8)));
typedef float f32x4 __attribute__((ext_vector_type(4)));

#define MFMA16(a, b, c) __builtin_amdgcn_mfma_f32_16x16x32_f16((a), (b), (c), 0, 0, 0)

// LDS-only barrier (does not force vmcnt drain).
__device__ __forceinline__ void soft_barrier() {
    asm volatile("s_waitcnt lgkmcnt(0)\n\ts_barrier" ::: "memory");
}

// ---------------------------------------------------------------------------
// Kernel 0: prep.
//   tiles 0..767    : hs fp32 -> hsf f16
//   tiles 768..1199 : W{q,k,v} -> wt f16 [(mat*12+h)*64+n][k]   (transposed)
//   tiles 1200..1259: ssan_w -> swt f16 [p][h][e][d]            (transposed)
//   tiles 1260..1323: dist_emb fp32 -> de16 f16
// ---------------------------------------------------------------------------
__global__ __launch_bounds__(256) void prep_kernel(
    const float* __restrict__ hs,
    const float* __restrict__ Wq, const float* __restrict__ Wk,
    const float* __restrict__ Wv, const float* __restrict__ sw,
    const float* __restrict__ de,
    f16* __restrict__ hsf, f16* __restrict__ wt, f16* __restrict__ swt,
    f16* __restrict__ de16)
{
    __shared__ float sT[64 * 66];
    const int t = threadIdx.x;
    const int tile = blockIdx.x;

    if (tile < 768) {
        const int base = tile * 2048 + t * 8;
        float4 a = *(const float4*)&hs[base];
        float4 b = *(const float4*)&hs[base + 4];
        f16x8 hv;
        hv[0] = (f16)a.x; hv[1] = (f16)a.y; hv[2] = (f16)a.z; hv[3] = (f16)a.w;
        hv[4] = (f16)b.x; hv[5] = (f16)b.y; hv[6] = (f16)b.z; hv[7] = (f16)b.w;
        *(f16x8*)&hsf[base] = hv;
        return;
    }
    if (tile >= 1260) {
        const int base = (tile - 1260) * 2048 + t * 8;
        if (base < 2047 * 64) {
            float4 a = *(const float4*)&de[base];
            float4 b = *(const float4*)&de[base + 4];
            f16x8 hv;
            hv[0] = (f16)a.x; hv[1] = (f16)a.y; hv[2] = (f16)a.z; hv[3] = (f16)a.w;
            hv[4] = (f16)b.x; hv[5] = (f16)b.y; hv[6] = (f16)b.z; hv[7] = (f16)b.w;
            *(f16x8*)&de16[base] = hv;
        }
        return;
    }

    const float* S; f16* D; int sRS, dRS;
    const int ti = tile - 768;
    if (ti < 432) {
        const int mat = ti / 144, r2 = ti % 144, ht = r2 / 12, kt = r2 % 12;
        const float* W = (mat == 0) ? Wq : (mat == 1) ? Wk : Wv;
        S = W + (size_t)(kt * 64) * ND + ht * 64;
        D = wt + (size_t)((mat * NH + ht) * 64) * ND + kt * 64;
        sRS = ND; dRS = ND;
    } else {
        const int i = ti - 432;
        S = sw + (size_t)i * 4096;
        D = swt + (size_t)i * 4096;
        sRS = 64; dRS = 64;
    }

    {
        const int kk = t >> 2, nb = (t & 3) * 16;
        float v[16];
        #pragma unroll
        for (int j = 0; j < 4; ++j)
            *(float4*)&v[4 * j] = *(const float4*)&S[(size_t)kk * sRS + nb + 4 * j];
        #pragma unroll
        for (int jj = 0; jj < 16; ++jj)
            sT[(nb + jj) * 66 + kk] = v[jj];
    }
    soft_barrier();
    {
        const int n = t >> 2, kb = (t & 3) * 16;
        f16 tmp[16];
        #pragma unroll
        for (int j = 0; j < 8; ++j) {
            float2 x = *(float2*)&sT[n * 66 + kb + 2 * j];
            tmp[2 * j]     = (f16)x.x;
            tmp[2 * j + 1] = (f16)x.y;
        }
        *(f16x8*)&D[(size_t)n * dRS + kb]     = *(f16x8*)&tmp[0];
        *(f16x8*)&D[(size_t)n * dRS + kb + 8] = *(f16x8*)&tmp[8];
    }
}

// ---------------------------------------------------------------------------
// Kernel A: QKV projection, f16 MFMA.  64x64 tile, 4 waves, 2x2 subtiles/wave.
// ---------------------------------------------------------------------------
__global__ __launch_bounds__(256, 4) void qkv_kernel(
    const f16* __restrict__ hsf, const f16* __restrict__ wt,
    const float* __restrict__ bq, const float* __restrict__ bk,
    const float* __restrict__ bv,
    f16* __restrict__ qf, f16* __restrict__ kf, f16* __restrict__ vt)
{
    __shared__ f16 sA[64 * 72], sB[64 * 72];
    __shared__ float sT[64 * 66];

    const int m0  = blockIdx.x * 64;
    const int y   = blockIdx.y;          // 0..35
    const int mat = y / NH, h = y % NH;
    const int t = threadIdx.x, lane = t & 63, w = t >> 6;
    const int quad = lane >> 4, l15 = lane & 15;
    const int wm = w >> 1, wn = w & 1;

    const float* bias = (mat == 0) ? bq : (mat == 1) ? bk : bv;

    f32x4 acc[2][2];
    #pragma unroll
    for (int r = 0; r < 2; ++r)
        #pragma unroll
        for (int c = 0; c < 2; ++c) acc[r][c] = (f32x4){0.f, 0.f, 0.f, 0.f};

    const int srow = t >> 2, scol = (t & 3) * 16;
    const f16* Ag = hsf + (size_t)(m0 + srow) * ND + scol;
    const f16* Bg = wt + ((size_t)y * 64 + srow) * ND + scol;

    for (int k0 = 0; k0 < ND; k0 += 64) {
        soft_barrier();
        *(f16x8*)&sA[srow * 72 + scol]     = *(const f16x8*)&Ag[k0];
        *(f16x8*)&sA[srow * 72 + scol + 8] = *(const f16x8*)&Ag[k0 + 8];
        *(f16x8*)&sB[srow * 72 + scol]     = *(const f16x8*)&Bg[k0];
        *(f16x8*)&sB[srow * 72 + scol + 8] = *(const f16x8*)&Bg[k0 + 8];
        soft_barrier();
        #pragma unroll
        for (int kk = 0; kk < 64; kk += 32) {
            const int ko = kk + quad * 8;
            f16x8 a0 = *(f16x8*)&sA[(32 * wm + l15) * 72 + ko];
            f16x8 a1 = *(f16x8*)&sA[(32 * wm + 16 + l15) * 72 + ko];
            f16x8 b0 = *(f16x8*)&sB[(32 * wn + l15) * 72 + ko];
            f16x8 b1 = *(f16x8*)&sB[(32 * wn + 16 + l15) * 72 + ko];
            acc[0][0] = MFMA16(a0, b0, acc[0][0]);
            acc[0][1] = MFMA16(a0, b1, acc[0][1]);
            acc[1][0] = MFMA16(a1, b0, acc[1][0]);
            acc[1][1] = MFMA16(a1, b1, acc[1][1]);
        }
    }
    soft_barrier();

    const int bb = m0 >> 10;
    const int lbase = m0 & 1023;
    const int bh = bb * NH + h;

    if (mat < 2) {
        #pragma unroll
        for (int r = 0; r < 2; ++r)
            #pragma unroll
            for (int c = 0; c < 2; ++c) {
                const int col = 32 * wn + 16 * c + l15;
                const float bz = bias[h * 64 + col];
                #pragma unroll
                for (int rr = 0; rr < 4; ++rr)
                    sT[(32 * wm + 16 * r + 4 * quad + rr) * 66 + col] = acc[r][c][rr] + bz;
            }
        soft_barrier();
        const int orow = t >> 2, ocb = (t & 3) * 16;
        f16 tmp[16];
        #pragma unroll
        for (int j = 0; j < 8; ++j) {
            float2 x = *(float2*)&sT[orow * 66 + ocb + 2 * j];
            tmp[2 * j] = (f16)x.x; tmp[2 * j + 1] = (f16)x.y;
        }
        f16* dst = ((mat == 0) ? qf : kf) + ((size_t)bh * NL + lbase + orow) * DH + ocb;
        *(f16x8*)dst       = *(f16x8*)&tmp[0];
        *(f16x8*)(dst + 8) = *(f16x8*)&tmp[8];
    } else {
        #pragma unroll
        for (int r = 0; r < 2; ++r)
            #pragma unroll
            for (int c = 0; c < 2; ++c) {
                const int col = 32 * wn + 16 * c + l15;
                const float bz = bias[h * 64 + col];
                #pragma unroll
                for (int rr = 0; rr < 4; ++rr)
                    sT[col * 66 + 32 * wm + 16 * r + 4 * quad + rr] = acc[r][c][rr] + bz;
            }
        soft_barrier();
        const int d = t >> 2, lcb = (t & 3) * 16;
        f16 tmp[16];
        #pragma unroll
        for (int j = 0; j < 8; ++j) {
            float2 x = *(float2*)&sT[d * 66 + lcb + 2 * j];
            tmp[2 * j] = (f16)x.x; tmp[2 * j + 1] = (f16)x.y;
        }
        f16* dst = vt + ((size_t)bh * DH + d) * NL + lbase + lcb;
        *(f16x8*)dst       = *(f16x8*)&tmp[0];
        *(f16x8*)(dst + 8) = *(f16x8*)&tmp[8];
    }
}

// ---------------------------------------------------------------------------
// Kernel B: qw[p,bh,l,e] = qf[bh,l,:] @ ssan_w[p,h]  via f16 MFMA (K=64).
// ---------------------------------------------------------------------------
__global__ __launch_bounds__(256, 4) void qw_kernel(
    const f16* __restrict__ qf, const f16* __restrict__ swt,
    f16* __restrict__ qwf)
{
    __shared__ f16 sA[64 * 72], sB[64 * 72];
    __shared__ float sT[64 * 66];

    const int l0 = blockIdx.x * 64;
    const int z  = blockIdx.y;      // 0..119
    const int p  = z / 24, bh = z % 24, h = bh % NH;
    const int t = threadIdx.x, lane = t & 63, w = t >> 6;
    const int quad = lane >> 4, l15 = lane & 15;
    const int wm = w >> 1, wn = w & 1;

    const int srow = t >> 2, scol = (t & 3) * 16;
    {
        const f16* As = qf + ((size_t)bh * NL + l0 + srow) * DH + scol;
        const f16* Bs = swt + ((size_t)(p * NH + h) * 64 + srow) * 64 + scol;
        *(f16x8*)&sA[srow * 72 + scol]     = *(const f16x8*)As;
        *(f16x8*)&sA[srow * 72 + scol + 8] = *(const f16x8*)(As + 8);
        *(f16x8*)&sB[srow * 72 + scol]     = *(const f16x8*)Bs;
        *(f16x8*)&sB[srow * 72 + scol + 8] = *(const f16x8*)(Bs + 8);
    }
    soft_barrier();

    f32x4 acc[2][2];
    #pragma unroll
    for (int r = 0; r < 2; ++r)
        #pragma unroll
        for (int c = 0; c < 2; ++c) acc[r][c] = (f32x4){0.f, 0.f, 0.f, 0.f};

    #pragma unroll
    for (int kk = 0; kk < 64; kk += 32) {
        const int ko = kk + quad * 8;
        f16x8 a0 = *(f16x8*)&sA[(32 * wm + l15) * 72 + ko];
        f16x8 a1 = *(f16x8*)&sA[(32 * wm + 16 + l15) * 72 + ko];
        f16x8 b0 = *(f16x8*)&sB[(32 * wn + l15) * 72 + ko];
        f16x8 b1 = *(f16x8*)&sB[(32 * wn + 16 + l15) * 72 + ko];
        acc[0][0] = MFMA16(a0, b0, acc[0][0]);
        acc[0][1] = MFMA16(a0, b1, acc[0][1]);
        acc[1][0] = MFMA16(a1, b0, acc[1][0]);
        acc[1][1] = MFMA16(a1, b1, acc[1][1]);
    }
    soft_barrier();

    #pragma unroll
    for (int r = 0; r < 2; ++r)
        #pragma unroll
        for (int c = 0; c < 2; ++c) {
            const int col = 32 * wn + 16 * c + l15;
            #pragma unroll
            for (int rr = 0; rr < 4; ++rr)
                sT[(32 * wm + 16 * r + 4 * quad + rr) * 66 + col] = acc[r][c][rr];
        }
    soft_barrier();

    const int orow = t >> 2, ocb = (t & 3) * 16;
    f16 tmp[16];
    #pragma unroll
    for (int j = 0; j < 8; ++j) {
        float2 x = *(float2*)&sT[orow * 66 + ocb + 2 * j];
        tmp[2 * j] = (f16)x.x; tmp[2 * j + 1] = (f16)x.y;
    }
    f16* dst = qwf + ((size_t)(p * 24 + bh) * NL + l0 + orow) * DH + ocb;
    *(f16x8*)dst       = *(f16x8*)&tmp[0];
    *(f16x8*)(dst + 8) = *(f16x8*)&tmp[8];
}

// ---------------------------------------------------------------------------
// Kernel C: f16-MFMA flash attention with fused positional band-GEMMs.
// 256 threads (4 waves), q-tile 32, k-tile 64, __launch_bounds__(256,2)
// (no-spill config: VGPR ~124).  Pos scratch: sQEl/sKEl [tp][row] pitch 34
// f16; stores are 4B-aligned f16x2 pairs (no same-dword write hazard),
// gathers <=3-way.  Per-wave slim tile assignment (12 MFMA/wave):
//   KE: jt=w, nt=3-w..5-w ;  QE: mi=msub, nt=3*npair+msub .. +qc-1.
// Coverage proof vs tp=i-j+63 ranges in session notes (round 7).
// ---------------------------------------------------------------------------
__global__ __launch_bounds__(256, 2) void attn_kernel(
    const f16* __restrict__ qf, const f16* __restrict__ kf,
    const f16* __restrict__ vt, const f16* __restrict__ qwf,
    const float* __restrict__ mask, const float* __restrict__ struct_m,
    const f16* __restrict__ de16, const float* __restrict__ abs_bias,
    float* __restrict__ out)
{
    __shared__ f16 sK[64 * 72];
    __shared__ f16 sVt[2][64 * 72];
    __shared__ f16 sE[96 * 72];      // E band rows 0..94 (t' = i-j+63)
    __shared__ f16 sQEl[96 * 34];    // [tp][i]
    __shared__ f16 sKEl[96 * 34];    // [tp][j]
    __shared__ float sS[32 * 68];
    __shared__ f16 sP[32 * 72];
    __shared__ float sAlpha[32], sL[32];

    const int l0 = blockIdx.x * 32;
    const int bh = blockIdx.y;
    const int bb = bh / NH, h = bh % NH;
    const int t  = threadIdx.x;
    const int lane  = t & 63;
    const int w     = t >> 6;       // 0..3
    const int quad  = lane >> 4;
    const int l15   = lane & 15;
    const int msub  = w >> 1;       // 0..1
    const int npair = w & 1;        // 0..1

    const size_t NQKV = (size_t)NB * NH * NL * DH;

    f16x8 aQ[2], aW[5][2];
    {
        const size_t qrow = ((size_t)bh * NL + l0 + 16 * msub + l15) * DH;
        #pragma unroll
        for (int K = 0; K < 2; ++K) {
            aQ[K] = *(const f16x8*)&qf[qrow + 32 * K + 8 * quad];
            #pragma unroll
            for (int p = 0; p < 5; ++p)
                aW[p][K] = *(const f16x8*)&qwf[p * NQKV + qrow + 32 * K + 8 * quad];
        }
    }

    float ab[5];
    #pragma unroll
    for (int p = 0; p < 5; ++p) ab[p] = abs_bias[p * NH + h];

    float pf_st[5][2][4], pf_mask[2];

    auto stage_kv = [&](int r0s, int buf) {
        const int row = t >> 3, col = (t & 7) * 8;
        const f16* ks = kf + ((size_t)bh * NL + r0s) * DH;
        *(f16x8*)&sK[row * 72 + col]        = *(const f16x8*)&ks[row * 64 + col];
        *(f16x8*)&sK[(row + 32) * 72 + col] = *(const f16x8*)&ks[(row + 32) * 64 + col];
        const f16* vs = vt + (size_t)bh * DH * NL + r0s;
        *(f16x8*)&sVt[buf][row * 72 + col] =
            *(const f16x8*)&vs[(size_t)row * NL + col];
        *(f16x8*)&sVt[buf][(row + 32) * 72 + col] =
            *(const f16x8*)&vs[(size_t)(row + 32) * NL + col];
    };
    auto stage_E = [&](int r0s) {
        const int ebase = l0 - r0s + 960;
        #pragma unroll
        for (int p2 = 0; p2 < 3; ++p2) {
            const int idx = t + 256 * p2;
            const int er = idx >> 3, col = (idx & 7) * 8;
            if (er < 95)
                *(f16x8*)&sE[er * 72 + col] =
                    *(const f16x8*)&de16[(size_t)(ebase + er) * DH + col];
        }
    };
    auto prefetch = [&](int r0s) {
        #pragma unroll
        for (int n = 0; n < 2; ++n) {
            const int j = 32 * npair + 16 * n + l15;
            pf_mask[n] = mask[bb * NL + r0s + j];
            #pragma unroll
            for (int r = 0; r < 4; ++r) {
                const int i = 16 * msub + 4 * quad + r;
                #pragma unroll
                for (int p = 0; p < 5; ++p)
                    pf_st[p][n][r] =
                        struct_m[((size_t)(p * NB + bb) * NL + l0 + i) * NL + r0s + j];
            }
        }
    };

    stage_kv(0, 0);
    stage_E(0);
    prefetch(0);

    const int sm_i = t >> 3;
    const int sm_jb = t & 7;
    float m_cur = -INFINITY, l_cur = 0.f;
    f32x4 O[2];
    O[0] = (f32x4){0.f, 0.f, 0.f, 0.f};
    O[1] = (f32x4){0.f, 0.f, 0.f, 0.f};

    for (int kt = 0; kt < 16; ++kt) {
        const int cur = kt & 1;
        soft_barrier();                    // staging of this kt visible

        // ---- Phase B: positional band GEMMs (slim per-wave assignment) ----
        {
            // KE: jt = w, nt = 3-w+c (c = 0..2)
            const int krow = (16 * w + l15) * 72;
            f16x8 ak0 = *(f16x8*)&sK[krow + quad * 8];
            f16x8 ak1 = *(f16x8*)&sK[krow + 32 + quad * 8];
            #pragma unroll
            for (int c = 0; c < 3; ++c) {
                const int nt = 3 - w + c;
                const int erow = (16 * nt + l15) * 72;
                f16x8 e0 = *(f16x8*)&sE[erow + quad * 8];
                f16x8 e1 = *(f16x8*)&sE[erow + 32 + quad * 8];
                f32x4 ck = (f32x4){0.f, 0.f, 0.f, 0.f};
                ck = MFMA16(ak0, e0, ck);
                ck = MFMA16(ak1, e1, ck);
                const int base = (16 * nt + l15) * 34 + 16 * w + 4 * quad;
                f16x2 lo = {(f16)ck[0], (f16)ck[1]};
                f16x2 hi = {(f16)ck[2], (f16)ck[3]};
                *(f16x2*)&sKEl[base]     = lo;
                *(f16x2*)&sKEl[base + 2] = hi;
            }
            // QE: mi = msub, nt = qs..qs+qc-1  (A-frag = resident aQ)
            const int qs = 3 * npair + msub;
            const int qc = 3 - npair;
            #pragma unroll
            for (int c = 0; c < 3; ++c) {
                if (c < qc) {
                    const int nt = qs + c;
                    const int erow = (16 * nt + l15) * 72;
                    f16x8 e0 = *(f16x8*)&sE[erow + quad * 8];
                    f16x8 e1 = *(f16x8*)&sE[erow + 32 + quad * 8];
                    f32x4 cq = (f32x4){0.f, 0.f, 0.f, 0.f};
                    cq = MFMA16(aQ[0], e0, cq);
                    cq = MFMA16(aQ[1], e1, cq);
                    const int base = (16 * nt + l15) * 34 + 16 * msub + 4 * quad;
                    f16x2 lo = {(f16)cq[0], (f16)cq[1]};
                    f16x2 hi = {(f16)cq[2], (f16)cq[3]};
                    *(f16x2*)&sQEl[base]     = lo;
                    *(f16x2*)&sQEl[base + 2] = hi;
                }
            }
        }
        soft_barrier();                    // sQEl/sKEl published

        // ---- Phase C: score MFMAs + epilogue (pos gather) ----
        {
            f32x4 acc[2][6];
            #pragma unroll
            for (int n = 0; n < 2; ++n)
                #pragma unroll
                for (int p = 0; p < 6; ++p)
                    acc[n][p] = (f32x4){0.f, 0.f, 0.f, 0.f};

            #pragma unroll
            for (int K = 0; K < 2; ++K) {
                const int koff = K * 32 + quad * 8;
                f16x8 bk2[2];
                #pragma unroll
                for (int n = 0; n < 2; ++n)
                    bk2[n] = *(f16x8*)&sK[(32 * npair + 16 * n + l15) * 72 + koff];
                #pragma unroll
                for (int n = 0; n < 2; ++n)
                    acc[n][0] = MFMA16(aQ[K], bk2[n], acc[n][0]);
                #pragma unroll
                for (int p = 0; p < 5; ++p)
                    #pragma unroll
                    for (int n = 0; n < 2; ++n)
                        acc[n][1 + p] = MFMA16(aW[p][K], bk2[n], acc[n][1 + p]);
            }

            #pragma unroll
            for (int n = 0; n < 2; ++n) {
                const int j = 32 * npair + 16 * n + l15;
                #pragma unroll
                for (int r = 0; r < 4; ++r) {
                    const int i = 16 * msub + 4 * quad + r;
                    const int tp = i - j + 63;
                    float posv = (float)sQEl[tp * 34 + i] + (float)sKEl[tp * 34 + j];
                    float s = (acc[n][0][r] + posv) * 0.125f + pf_mask[n];
                    #pragma unroll
                    for (int p = 0; p < 5; ++p)
                        s += (acc[n][1 + p][r] + ab[p]) * pf_st[p][n][r];
                    sS[i * 68 + j] = s;
                }
            }
        }
        soft_barrier();                    // sS published

        // ---- Phase D: online softmax ----
        {
            float sv[8];
            float smax = -INFINITY;
            #pragma unroll
            for (int k = 0; k < 8; ++k) {
                sv[k] = sS[sm_i * 68 + sm_jb + 8 * k];
                smax = fmaxf(smax, sv[k]);
            }
            #pragma unroll
            for (int off = 4; off > 0; off >>= 1)
                smax = fmaxf(smax, __shfl_xor(smax, off, 8));
            const float m_new = fmaxf(m_cur, smax);
            const float alpha = __expf(m_cur - m_new);
            float rsum = 0.f;
            #pragma unroll
            for (int k = 0; k < 8; ++k) {
                float p = __expf(sv[k] - m_new);
                sP[sm_i * 72 + sm_jb + 8 * k] = (f16)p;
                rsum += p;
            }
            #pragma unroll
            for (int off = 4; off > 0; off >>= 1)
                rsum += __shfl_xor(rsum, off, 8);
            l_cur = l_cur * alpha + rsum;
            m_cur = m_new;
            if (sm_jb == 0) { sAlpha[sm_i] = alpha; sL[sm_i] = l_cur; }
        }
        soft_barrier();                    // sP/alpha published

        // ---- Phase E: issue next-kt VMEM first, then PV MFMA ----
        {
            if (kt < 15) {
                stage_kv((kt + 1) * 64, cur ^ 1);
                stage_E((kt + 1) * 64);
                prefetch((kt + 1) * 64);
            }

            float a4[4];
            #pragma unroll
            for (int r = 0; r < 4; ++r) a4[r] = sAlpha[16 * msub + 4 * quad + r];
            #pragma unroll
            for (int n = 0; n < 2; ++n)
                #pragma unroll
                for (int r = 0; r < 4; ++r) O[n][r] *= a4[r];

            const int prow = (16 * msub + l15) * 72;
            #pragma unroll
            for (int K = 0; K < 2; ++K) {
                const int koff = K * 32 + quad * 8;
                f16x8 pfr = *(f16x8*)&sP[prow + koff];
                #pragma unroll
                for (int n = 0; n < 2; ++n) {
                    f16x8 vfr = *(f16x8*)&sVt[cur][(32 * npair + 16 * n + l15) * 72 + koff];
                    O[n] = MFMA16(pfr, vfr, O[n]);
                }
            }
        }
    }

    float linv[4];
    #pragma unroll
    for (int r = 0; r < 4; ++r) linv[r] = 1.0f / sL[16 * msub + 4 * quad + r];
    #pragma unroll
    for (int n = 0; n < 2; ++n) {
        const int dh = 32 * npair + 16 * n + l15;
        #pragma unroll
        for (int r = 0; r < 4; ++r) {
            const int i = 16 * msub + 4 * quad + r;
            out[((size_t)bb * NL + l0 + i) * ND + h * DH + dh] = O[n][r] * linv[r];
        }
    }
}

// ---------------------------------------------------------------------------
extern "C" void kernel_launch(void* const* d_in, const int* in_sizes, int n_in,
                              void* d_out, int out_size, void* d_ws, size_t ws_size,
                              hipStream_t stream) {
    const float* hs   = (const float*)d_in[0];
    const float* mask = (const float*)d_in[1];
    const float* stm  = (const float*)d_in[2];
    const float* Wq   = (const float*)d_in[3];
    const float* bq   = (const float*)d_in[4];
    const float* Wk   = (const float*)d_in[5];
    const float* bk   = (const float*)d_in[6];
    const float* Wv   = (const float*)d_in[7];
    const float* bv   = (const float*)d_in[8];
    const float* de   = (const float*)d_in[9];
    const float* sw   = (const float*)d_in[10];
    const float* abb  = (const float*)d_in[11];
    float* outp = (float*)d_out;

    const size_t NQKV = (size_t)NB * NH * NL * DH;       // 1,572,864
    char* ws = (char*)d_ws;
    f16* qf   = (f16*)ws;                 ws += NQKV * 2;
    f16* kf   = (f16*)ws;                 ws += NQKV * 2;
    f16* vtb  = (f16*)ws;                 ws += NQKV * 2;
    f16* qwf  = (f16*)ws;                 ws += 5 * NQKV * 2;
    f16* hsf  = (f16*)ws;                 ws += NQKV * 2;
    f16* wt   = (f16*)ws;                 ws += (size_t)2304 * 768 * 2;
    f16* swt  = (f16*)ws;                 ws += (size_t)245760 * 2;
    f16* de16 = (f16*)ws;                 // 2047*64 f16 = 262 KB

    prep_kernel<<<1324, 256, 0, stream>>>(hs, Wq, Wk, Wv, sw, de,
                                          hsf, wt, swt, de16);
    qkv_kernel<<<dim3(32, 36), 256, 0, stream>>>(hsf, wt, bq, bk, bv, qf, kf, vtb);
    qw_kernel<<<dim3(16, 120), 256, 0, stream>>>(qf, swt, qwf);
    attn_kernel<<<dim3(32, 24), 256, 0, stream>>>(qf, kf, vtb, qwf,
                                                  mask, stm, de16, abb, outp);
}